// Round 17
// baseline (546.614 us; speedup 1.0000x reference)
//
#include <hip/hip_runtime.h>

#define V_ 10000
#define D_ 256
#define T_ 128
#define B_ 8
#define MS_ 4
#define S_ 5
#define EOS_ 4

typedef unsigned short b16_t;
typedef __attribute__((ext_vector_type(8))) short s16x8;
typedef __attribute__((ext_vector_type(8))) unsigned short u16x8;
typedef __attribute__((ext_vector_type(4))) float f32x4;
typedef __attribute__((ext_vector_type(2))) _Float16 h16x2;

__device__ inline b16_t f2bf(float f) {
  union { float f; unsigned u; } v; v.f = f;
  unsigned r = v.u + 0x7FFFu + ((v.u >> 16) & 1u);
  return (b16_t)(r >> 16);
}
__device__ inline float bf2f(b16_t h) {
  union { unsigned u; float f; } v; v.u = ((unsigned)h) << 16; return v.f;
}
__device__ inline float sigm_(float x) { return 1.0f / (1.0f + __expf(-x)); }
__device__ inline float tanh_(float x) { return 2.0f / (1.0f + __expf(-2.0f * x)) - 1.0f; }
__device__ inline h16x2 bch(unsigned u) { return __builtin_bit_cast(h16x2, u); }
__device__ inline unsigned pkh(float a, float b) {
  h16x2 v; v.x = (_Float16)a; v.y = (_Float16)b;
  return __builtin_bit_cast(unsigned, v);
}

#if __has_builtin(__builtin_amdgcn_fdot2)
#define FDOT2(a, b, c) __builtin_amdgcn_fdot2((a), (b), (c), false)
#else
#define FDOT2(a, b, c) ((c) + (float)(a).x * (float)(b).x + (float)(a).y * (float)(b).y)
#endif

// quad_perm swaps (VALU DPP, not LDS pipe)
__device__ inline float qswap1(float x) {   // lanes l <-> l^1
  return __builtin_bit_cast(float, __builtin_amdgcn_update_dpp(
      0, __builtin_bit_cast(int, x), 0xB1, 0xF, 0xF, true));
}
__device__ inline float qswap2(float x) {   // lanes l <-> l^2
  return __builtin_bit_cast(float, __builtin_amdgcn_update_dpp(
      0, __builtin_bit_cast(int, x), 0x4E, 0xF, 0xF, true));
}

// ---------------- prep: weight casts + seq + seg(s>=1) ----------------
__device__ inline void cvt4(const float* __restrict__ s, b16_t* __restrict__ d) {
  float4 v = *(const float4*)s;
  ushort4 o = { f2bf(v.x), f2bf(v.y), f2bf(v.z), f2bf(v.w) };
  *(ushort4*)d = o;
}

__global__ void k_prep(const float* __restrict__ emb, const float* __restrict__ cWi,
                       const float* __restrict__ y0W, const float* __restrict__ hlW,
                       const float* __restrict__ l0Wi, const float* __restrict__ l0Wh,
                       const float* __restrict__ l1Wi, const float* __restrict__ l1Wh,
                       const float* __restrict__ cWh, const int* __restrict__ x_ids,
                       const float* __restrict__ y_st,
                       b16_t* __restrict__ emb_bf, b16_t* __restrict__ cWi_bf,
                       b16_t* __restrict__ y0W_bf, b16_t* __restrict__ hlW_bf,
                       b16_t* __restrict__ l0Wi_bf, b16_t* __restrict__ l0Wh_bf,
                       b16_t* __restrict__ Wcat_bf, unsigned* __restrict__ Whf,
                       b16_t* __restrict__ seq_bf, b16_t* __restrict__ seg_bf) {
  for (long i = (long)blockIdx.x * blockDim.x + threadIdx.x; i < 1410048L;
       i += (long)gridDim.x * blockDim.x) {
    if (i < 640000L) { cvt4(emb + i * 4, emb_bf + i * 4); }
    else if (i < 705536L) { long j = i - 640000L; cvt4(cWi + j * 4, cWi_bf + j * 4); }
    else if (i < 721920L) { long j = i - 705536L; cvt4(y0W + j * 4, y0W_bf + j * 4); }
    else if (i < 754688L) { long j = i - 721920L; cvt4(hlW + j * 4, hlW_bf + j * 4); }
    else if (i < 820224L) { long j = i - 754688L; cvt4(l0Wi + j * 4, l0Wi_bf + j * 4); }
    else if (i < 885760L) { long j = i - 820224L; cvt4(l0Wh + j * 4, l0Wh_bf + j * 4); }
    else if (i < 1016832L) {
      long j = (i - 885760L) * 4;
      long n = j >> 9; int k = (int)(j & 511);
      const float* src = (k < 256) ? (l1Wi + n * 256 + k) : (l1Wh + n * 256 + (k - 256));
      cvt4(src, Wcat_bf + j);
    } else if (i < 1082368L) {
      long j = i - 1016832L;
      float4 v = *(const float4*)(cWh + j * 4);
      Whf[2 * j] = pkh(v.x, v.y);
      Whf[2 * j + 1] = pkh(v.z, v.w);
    } else if (i < 1147904L) {
      long j = i - 1082368L;                    // seq_bf: [1024][256]
      int m = (int)(j >> 6), c = (int)(j & 63) * 4;
      int t = m >> 3, b = m & 7;
      const float* src = (t == 0) ? (y_st + c)
                                  : (emb + (size_t)x_ids[b * (T_ + 2) + t] * D_ + c);
      cvt4(src, seq_bf + (size_t)m * D_ + c);
    } else {
      long j = i - 1147904L;                    // seg rows s>=1: 4096 rows x 64 chunks
      int r = (int)(j >> 6), c = (int)(j & 63) * 4;
      int p = r >> 2, s = 1 + (r & 3);
      int t = p >> 3, b = p & 7;
      int tt = t + s - 1;
      int ps = r + (r >> 2) + 1;                // = p*5 + s
      if (tt < T_) {
        int tok = x_ids[b * (T_ + 2) + tt + 1];
        cvt4(emb + (size_t)tok * D_ + c, seg_bf + (size_t)ps * 256 + c);
      } else {
        ushort4 z = {0, 0, 0, 0};
        *(ushort4*)(seg_bf + (size_t)ps * 256 + c) = z;
      }
    }
  }
}

// ------- generic bf16 MFMA GEMM (K=256): C = A @ Bw^T + bias -------
__global__ __launch_bounds__(256) void k_gemm(const b16_t* __restrict__ A, int lda,
                                              const b16_t* __restrict__ Bw,
                                              const float* __restrict__ bias,
                                              float* __restrict__ C, int ldc) {
  __shared__ b16_t As[64][264];
  __shared__ b16_t Bs[64][264];
  int tid = threadIdx.x;
  int rowBase = blockIdx.x * 64, colBase = blockIdx.y * 64;
  for (int i = tid; i < 64 * 32; i += 256) {
    int r = i >> 5, c = (i & 31) * 8;
    *(u16x8*)&As[r][c] = *(const u16x8*)(A + (size_t)(rowBase + r) * lda + c);
    *(u16x8*)&Bs[r][c] = *(const u16x8*)(Bw + (size_t)(colBase + r) * 256 + c);
  }
  __syncthreads();
  int w = tid >> 6, l = tid & 63, lr = l & 15, kg = l >> 4;
  f32x4 acc[4] = {{0.f,0.f,0.f,0.f},{0.f,0.f,0.f,0.f},{0.f,0.f,0.f,0.f},{0.f,0.f,0.f,0.f}};
  f32x4 acc2[4] = {{0.f,0.f,0.f,0.f},{0.f,0.f,0.f,0.f},{0.f,0.f,0.f,0.f},{0.f,0.f,0.f,0.f}};
  for (int kk = 0; kk < 4; ++kk) {
    s16x8 a = *(const s16x8*)&As[w * 16 + lr][kk * 32 + kg * 8];
    s16x8 a2 = *(const s16x8*)&As[w * 16 + lr][(kk + 4) * 32 + kg * 8];
#pragma unroll
    for (int f = 0; f < 4; ++f) {
      s16x8 b = *(const s16x8*)&Bs[f * 16 + lr][kk * 32 + kg * 8];
      s16x8 b2 = *(const s16x8*)&Bs[f * 16 + lr][(kk + 4) * 32 + kg * 8];
      acc[f] = __builtin_amdgcn_mfma_f32_16x16x32_bf16(a, b, acc[f], 0, 0, 0);
      acc2[f] = __builtin_amdgcn_mfma_f32_16x16x32_bf16(a2, b2, acc2[f], 0, 0, 0);
    }
  }
#pragma unroll
  for (int f = 0; f < 4; ++f) {
#pragma unroll
    for (int r = 0; r < 4; ++r) {
      int m = rowBase + w * 16 + kg * 4 + r;
      int n = colBase + f * 16 + lr;
      C[(size_t)m * ldc + n] = acc[f][r] + acc2[f][r] + bias[n];
    }
  }
}

// ---- fused: encoder v9 (blocks 0..31) + X0 s>=1 GEMM (blocks 32..1055) ----
#define ENC_Q4(i0)                                                             \
  do {                                                                         \
    uint4 a0 = hp[i0], a1 = hp[i0 + 1], a2 = hp[i0 + 2], a3 = hp[i0 + 3];      \
    s0 = FDOT2(bch(a0.x), bch(wv[4 * (i0) + 0]), s0);                          \
    s1 = FDOT2(bch(a0.x), bch(wv[32 + 4 * (i0) + 0]), s1);                     \
    s0 = FDOT2(bch(a0.y), bch(wv[4 * (i0) + 1]), s0);                          \
    s1 = FDOT2(bch(a0.y), bch(wv[32 + 4 * (i0) + 1]), s1);                     \
    s0 = FDOT2(bch(a0.z), bch(wv[4 * (i0) + 2]), s0);                          \
    s1 = FDOT2(bch(a0.z), bch(wv[32 + 4 * (i0) + 2]), s1);                     \
    s0 = FDOT2(bch(a0.w), bch(wv[4 * (i0) + 3]), s0);                          \
    s1 = FDOT2(bch(a0.w), bch(wv[32 + 4 * (i0) + 3]), s1);                     \
    s0 = FDOT2(bch(a1.x), bch(wv[4 * (i0) + 4]), s0);                          \
    s1 = FDOT2(bch(a1.x), bch(wv[32 + 4 * (i0) + 4]), s1);                     \
    s0 = FDOT2(bch(a1.y), bch(wv[4 * (i0) + 5]), s0);                          \
    s1 = FDOT2(bch(a1.y), bch(wv[32 + 4 * (i0) + 5]), s1);                     \
    s0 = FDOT2(bch(a1.z), bch(wv[4 * (i0) + 6]), s0);                          \
    s1 = FDOT2(bch(a1.z), bch(wv[32 + 4 * (i0) + 6]), s1);                     \
    s0 = FDOT2(bch(a1.w), bch(wv[4 * (i0) + 7]), s0);                          \
    s1 = FDOT2(bch(a1.w), bch(wv[32 + 4 * (i0) + 7]), s1);                     \
    s0 = FDOT2(bch(a2.x), bch(wv[4 * (i0) + 8]), s0);                          \
    s1 = FDOT2(bch(a2.x), bch(wv[32 + 4 * (i0) + 8]), s1);                     \
    s0 = FDOT2(bch(a2.y), bch(wv[4 * (i0) + 9]), s0);                          \
    s1 = FDOT2(bch(a2.y), bch(wv[32 + 4 * (i0) + 9]), s1);                     \
    s0 = FDOT2(bch(a2.z), bch(wv[4 * (i0) + 10]), s0);                         \
    s1 = FDOT2(bch(a2.z), bch(wv[32 + 4 * (i0) + 10]), s1);                    \
    s0 = FDOT2(bch(a2.w), bch(wv[4 * (i0) + 11]), s0);                         \
    s1 = FDOT2(bch(a2.w), bch(wv[32 + 4 * (i0) + 11]), s1);                    \
    s0 = FDOT2(bch(a3.x), bch(wv[4 * (i0) + 12]), s0);                         \
    s1 = FDOT2(bch(a3.x), bch(wv[32 + 4 * (i0) + 12]), s1);                    \
    s0 = FDOT2(bch(a3.y), bch(wv[4 * (i0) + 13]), s0);                         \
    s1 = FDOT2(bch(a3.y), bch(wv[32 + 4 * (i0) + 13]), s1);                    \
    s0 = FDOT2(bch(a3.z), bch(wv[4 * (i0) + 14]), s0);                         \
    s1 = FDOT2(bch(a3.z), bch(wv[32 + 4 * (i0) + 14]), s1);                    \
    s0 = FDOT2(bch(a3.w), bch(wv[4 * (i0) + 15]), s0);                         \
    s1 = FDOT2(bch(a3.w), bch(wv[32 + 4 * (i0) + 15]), s1);                    \
  } while (0)

struct EncS { unsigned hbuf[144]; float gl[256]; };   // hbuf: quarter c at c*36
struct GemS { b16_t As[64][264]; b16_t Bs[64][264]; };

__global__ __launch_bounds__(512, 2) void k_enc_x0(
    const unsigned* __restrict__ Whf,    // [1024][128] f16-pair packed
    const float* __restrict__ encX,      // [1024][1024] (plain, L2-cached)
    unsigned* __restrict__ hglob,        // [128][8][4][32] dwords, ZEROED each call
    b16_t* __restrict__ droph,           // [1024][256]
    const b16_t* __restrict__ seg_bf, const b16_t* __restrict__ l0Wi_bf,
    const float* __restrict__ l0b, float* __restrict__ X0) {
  __shared__ union { EncS e; GemS g; } sm;
  int tid = threadIdx.x;
  if (blockIdx.x < 32) {
    // ================= encoder v9 (value-based cross-block sync) =================
    int b = blockIdx.x & 7, q = blockIdx.x >> 3;
    int rp = tid >> 2, cq = tid & 3;
    int r0l = 2 * rp;                           // local rows r0l, r0l+1
    int grow0 = ((r0l >> 6) << 8) + q * 64 + (r0l & 63);   // grow1 = grow0 + 1
    unsigned wv[64];                            // rows 2rp,2rp+1 x dwords [cq*32,+32)
    {
      const uint4* wp0 = (const uint4*)(Whf + (size_t)grow0 * 128 + cq * 32);
      const uint4* wp1 = (const uint4*)(Whf + (size_t)(grow0 + 1) * 128 + cq * 32);
#pragma unroll
      for (int i = 0; i < 8; ++i) {
        uint4 v = wp0[i];
        wv[4*i] = v.x; wv[4*i+1] = v.y; wv[4*i+2] = v.z; wv[4*i+3] = v.w;
      }
#pragma unroll
      for (int i = 0; i < 8; ++i) {
        uint4 v = wp1[i];
        wv[32+4*i] = v.x; wv[32+4*i+1] = v.y; wv[32+4*i+2] = v.z; wv[32+4*i+3] = v.w;
      }
    }
#pragma unroll
    for (int i = 0; i < 64; ++i) asm volatile("" : "+v"(wv[i]));
    if (tid < 144) sm.e.hbuf[tid] = 0;
    float c = 0.f;                              // live for tid<64 (dl = tid)
    float ex = encX[(size_t)b * 1024 + grow0 + (cq & 1)];
    __syncthreads();
#pragma unroll 1
    for (int t = 0; t < 128; ++t) {
      const uint4* hp = (const uint4*)&sm.e.hbuf[cq * 36];
      float s0 = 0.f, s1 = 0.f;
      ENC_Q4(0);
      __builtin_amdgcn_sched_barrier(0);
      ENC_Q4(4);
      // reduce over 4 col-quarters (lanes cq=0..3) — pure DPP
      s0 += qswap1(s0); s0 += qswap2(s0);
      s1 += qswap1(s1); s1 += qswap2(s1);
      if (cq == 0) sm.e.gl[r0l] = s0 + ex;
      else if (cq == 1) sm.e.gl[r0l + 1] = s1 + ex;
      __syncthreads();                          // gl ready; hbuf reads of step t done
      if (tid < 64) {
        float gi = sm.e.gl[tid], gf = sm.e.gl[64 + tid];
        float gg = sm.e.gl[128 + tid], go = sm.e.gl[192 + tid];
        float c2 = sigm_(gf) * c + sigm_(gi) * tanh_(gg);
        float h2 = sigm_(go) * tanh_(c2);
        c = c2;
        float hnb = qswap1(h2);
        if ((tid & 1) == 0) {
          // tag: both f16 mantissa LSBs forced nonzero -> dword never 0.
          unsigned pk = pkh(h2, hnb) | 0x00010001u;
          sm.e.hbuf[q * 36 + (tid >> 1)] = pk;
          if (t < 127)
            __hip_atomic_store(&hglob[(((size_t)t * 8 + b) * 4 + q) * 32 + (tid >> 1)],
                               pk, __ATOMIC_RELAXED, __HIP_MEMORY_SCOPE_AGENT);
        }
        droph[((size_t)t * 8 + b) * 256 + q * 64 + tid] = f2bf(0.1f * h2);
      }
      if (t < 127) {
        if (tid >= 64 && tid < 160) {           // waves 1-2: gather 3 remote quarters
          int idx = tid - 64;
          int ro = idx >> 5;
          int rq = ro + (ro >= q);
          int dw = idx & 31;
          unsigned* src = &hglob[(((size_t)t * 8 + b) * 4 + rq) * 32 + dw];
          unsigned v;
          do {
            v = __hip_atomic_load(src, __ATOMIC_RELAXED, __HIP_MEMORY_SCOPE_AGENT);
          } while (v == 0u);                    // value-based: nonzero == ready
          sm.e.hbuf[rq * 36 + dw] = v;
        }
        ex = encX[((size_t)(t + 1) * 8 + b) * 1024 + grow0 + (cq & 1)];
        __syncthreads();                        // hbuf = full h_{t+1}
      }
    }
  } else {
    // ================= X0 rows s>=1: ps(j) = j + j/4 + 1 =================
    int bx2 = blockIdx.x - 32;             // 0..1023 = 64 row-blocks x 16 col-blocks
    int rb = (bx2 & 63) * 64;
    int colBase = (bx2 >> 6) * 64;
    if (tid < 256) {
      for (int i = tid; i < 64 * 32; i += 256) {
        int r = i >> 5, cc = (i & 31) * 8;
        int jj = rb + r, ps = jj + (jj >> 2) + 1;
        *(u16x8*)&sm.g.As[r][cc] = *(const u16x8*)(seg_bf + (size_t)ps * 256 + cc);
        *(u16x8*)&sm.g.Bs[r][cc] = *(const u16x8*)(l0Wi_bf + (size_t)(colBase + r) * 256 + cc);
      }
    }
    __syncthreads();
    if (tid < 256) {
      int w = tid >> 6, l = tid & 63, lr = l & 15, kg = l >> 4;
      f32x4 acc[4] = {{0.f,0.f,0.f,0.f},{0.f,0.f,0.f,0.f},{0.f,0.f,0.f,0.f},{0.f,0.f,0.f,0.f}};
      f32x4 acc2[4] = {{0.f,0.f,0.f,0.f},{0.f,0.f,0.f,0.f},{0.f,0.f,0.f,0.f},{0.f,0.f,0.f,0.f}};
      for (int kk = 0; kk < 4; ++kk) {
        s16x8 a = *(const s16x8*)&sm.g.As[w * 16 + lr][kk * 32 + kg * 8];
        s16x8 a2 = *(const s16x8*)&sm.g.As[w * 16 + lr][(kk + 4) * 32 + kg * 8];
#pragma unroll
        for (int f = 0; f < 4; ++f) {
          s16x8 b = *(const s16x8*)&sm.g.Bs[f * 16 + lr][kk * 32 + kg * 8];
          s16x8 b2 = *(const s16x8*)&sm.g.Bs[f * 16 + lr][(kk + 4) * 32 + kg * 8];
          acc[f] = __builtin_amdgcn_mfma_f32_16x16x32_bf16(a, b, acc[f], 0, 0, 0);
          acc2[f] = __builtin_amdgcn_mfma_f32_16x16x32_bf16(a2, b2, acc2[f], 0, 0, 0);
        }
      }
#pragma unroll
      for (int f = 0; f < 4; ++f) {
#pragma unroll
        for (int r = 0; r < 4; ++r) {
          int jj = rb + w * 16 + kg * 4 + r;
          int ps = jj + (jj >> 2) + 1;
          int n = colBase + f * 16 + lr;
          X0[(size_t)ps * 1024 + n] = acc[f][r] + acc2[f][r] + l0b[n];
        }
      }
    }
  }
}

// ---- fused projections + X0 s=0: y_in0 -> seg(s=0), hlin -> hcat, X0 s0 GEMM ----
__global__ __launch_bounds__(256) void k_proj(
    const b16_t* __restrict__ droph, const b16_t* __restrict__ y0W_bf,
    const float* __restrict__ y0b, const b16_t* __restrict__ hlW_bf,
    const float* __restrict__ hlb, b16_t* __restrict__ seg_bf,
    b16_t* __restrict__ hcat,
    const b16_t* __restrict__ l0Wi_bf, const float* __restrict__ l0b,
    float* __restrict__ X0) {
  __shared__ b16_t As[64][264];
  __shared__ b16_t Bs[64][264];
  int bx = blockIdx.x, by = blockIdx.y;
  const b16_t* Ab; int lda;
  const b16_t* Bw; const float* bias; int colBase, mode;
  if (by < 4)       { Ab = droph;  lda = 256;  Bw = y0W_bf;  bias = y0b; colBase = by * 64;        mode = 0; }
  else if (by < 12) { Ab = droph;  lda = 256;  Bw = hlW_bf;  bias = hlb; colBase = (by - 4) * 64;  mode = 1; }
  else              { Ab = seg_bf; lda = 1280; Bw = l0Wi_bf; bias = l0b; colBase = (by - 12) * 64; mode = 2; }
  int rowBase = bx * 64;
  int tid = threadIdx.x;
  for (int i = tid; i < 64 * 32; i += 256) {
    int r = i >> 5, c = (i & 31) * 8;
    *(u16x8*)&As[r][c] = *(const u16x8*)(Ab + (size_t)(rowBase + r) * lda + c);
    *(u16x8*)&Bs[r][c] = *(const u16x8*)(Bw + (size_t)(colBase + r) * 256 + c);
  }
  __syncthreads();
  int w = tid >> 6, l = tid & 63, lr = l & 15, kg = l >> 4;
  f32x4 acc[4] = {{0.f,0.f,0.f,0.f},{0.f,0.f,0.f,0.f},{0.f,0.f,0.f,0.f},{0.f,0.f,0.f,0.f}};
  f32x4 acc2[4] = {{0.f,0.f,0.f,0.f},{0.f,0.f,0.f,0.f},{0.f,0.f,0.f,0.f},{0.f,0.f,0.f,0.f}};
  for (int kk = 0; kk < 4; ++kk) {
    s16x8 a = *(const s16x8*)&As[w * 16 + lr][kk * 32 + kg * 8];
    s16x8 a2 = *(const s16x8*)&As[w * 16 + lr][(kk + 4) * 32 + kg * 8];
#pragma unroll
    for (int f = 0; f < 4; ++f) {
      s16x8 b = *(const s16x8*)&Bs[f * 16 + lr][kk * 32 + kg * 8];
      s16x8 b2 = *(const s16x8*)&Bs[f * 16 + lr][(kk + 4) * 32 + kg * 8];
      acc[f] = __builtin_amdgcn_mfma_f32_16x16x32_bf16(a, b, acc[f], 0, 0, 0);
      acc2[f] = __builtin_amdgcn_mfma_f32_16x16x32_bf16(a2, b2, acc2[f], 0, 0, 0);
    }
  }
#pragma unroll
  for (int f = 0; f < 4; ++f) {
#pragma unroll
    for (int r = 0; r < 4; ++r) {
      int m = rowBase + w * 16 + kg * 4 + r;
      int n = colBase + f * 16 + lr;
      float v = acc[f][r] + acc2[f][r] + bias[n];
      if (mode == 0) seg_bf[(size_t)m * 1280 + n] = f2bf(v);
      else if (mode == 1) hcat[(size_t)m * 512 + n] = f2bf(tanh_(v));
      else X0[(size_t)m * 5120 + n] = v;       // X0 row m*5 (s=0)
    }
  }
}

// ---------------- fused decoder step: both layers + cells, 64 blocks ----------------
__global__ __launch_bounds__(512) void k_dec2(
    b16_t* __restrict__ hcat,            // [1024][512] : [h0 | h1] bf16
    const b16_t* __restrict__ l0Wh_bf,   // [1024][256]
    const b16_t* __restrict__ Wcat_bf,   // [1024][512]  ([l1Wi | l1Wh])
    const float* __restrict__ X0,        // [5120][1024]
    const float* __restrict__ l1b,
    float* __restrict__ c0, float* __restrict__ c1,
    b16_t* __restrict__ dec_out, int s) {
  __shared__ b16_t A0s[16][264];
  __shared__ b16_t A1s[16][520];
  int tid = threadIdx.x;
  int R0 = blockIdx.x * 16;
  for (int i = tid; i < 16 * 32; i += 512) {
    int r = i >> 5, cc = (i & 31) * 8;
    *(u16x8*)&A0s[r][cc] = *(const u16x8*)(hcat + (size_t)(R0 + r) * 512 + cc);
    *(u16x8*)&A1s[r][256 + cc] = *(const u16x8*)(hcat + (size_t)(R0 + r) * 512 + 256 + cc);
  }
  __syncthreads();
  int w = tid >> 6, l = tid & 63, lr = l & 15, kg = l >> 4;
  {
    s16x8 af[8];
#pragma unroll
    for (int kk = 0; kk < 8; ++kk)
      af[kk] = *(const s16x8*)&A0s[lr][kk * 32 + kg * 8];
    f32x4 acc[4][2];
#pragma unroll
    for (int g = 0; g < 4; ++g)
#pragma unroll
      for (int ct = 0; ct < 2; ++ct) acc[g][ct] = f32x4{0.f, 0.f, 0.f, 0.f};
#pragma unroll
    for (int g = 0; g < 4; ++g)
#pragma unroll
      for (int ct = 0; ct < 2; ++ct) {
        int n = g * 256 + w * 32 + ct * 16 + lr;
        const b16_t* bp = l0Wh_bf + (size_t)n * 256 + kg * 8;
#pragma unroll
        for (int kk = 0; kk < 8; ++kk)
          acc[g][ct] = __builtin_amdgcn_mfma_f32_16x16x32_bf16(
              af[kk], *(const s16x8*)(bp + kk * 32), acc[g][ct], 0, 0, 0);
      }
#pragma unroll
    for (int ct = 0; ct < 2; ++ct)
#pragma unroll
      for (int r = 0; r < 4; ++r) {
        int row = kg * 4 + r, p = R0 + row, d = w * 32 + ct * 16 + lr;
        const float* xp = X0 + ((size_t)p * 5 + s) * 1024;
        float gi = acc[0][ct][r] + xp[d],       gf = acc[1][ct][r] + xp[256 + d];
        float gg = acc[2][ct][r] + xp[512 + d], go = acc[3][ct][r] + xp[768 + d];
        float cc0 = c0[(size_t)p * 256 + d];
        float c2 = sigm_(gf) * cc0 + sigm_(gi) * tanh_(gg);
        float h2 = sigm_(go) * tanh_(c2);
        c0[(size_t)p * 256 + d] = c2;
        b16_t hb = f2bf(h2);
        A1s[row][d] = hb;
        hcat[(size_t)p * 512 + d] = hb;
      }
  }
  __syncthreads();
  {
    s16x8 a1[16];
#pragma unroll
    for (int kk = 0; kk < 16; ++kk)
      a1[kk] = *(const s16x8*)&A1s[lr][kk * 32 + kg * 8];
    f32x4 acc[4][2];
#pragma unroll
    for (int g = 0; g < 4; ++g)
#pragma unroll
      for (int ct = 0; ct < 2; ++ct) acc[g][ct] = f32x4{0.f, 0.f, 0.f, 0.f};
#pragma unroll
    for (int g = 0; g < 4; ++g)
#pragma unroll
      for (int ct = 0; ct < 2; ++ct) {
        int n = g * 256 + w * 32 + ct * 16 + lr;
        const b16_t* bp = Wcat_bf + (size_t)n * 512 + kg * 8;
#pragma unroll
        for (int kk = 0; kk < 16; ++kk)
          acc[g][ct] = __builtin_amdgcn_mfma_f32_16x16x32_bf16(
              a1[kk], *(const s16x8*)(bp + kk * 32), acc[g][ct], 0, 0, 0);
      }
#pragma unroll
    for (int ct = 0; ct < 2; ++ct)
#pragma unroll
      for (int r = 0; r < 4; ++r) {
        int row = kg * 4 + r, p = R0 + row, d = w * 32 + ct * 16 + lr;
        float gi = acc[0][ct][r] + l1b[d],       gf = acc[1][ct][r] + l1b[256 + d];
        float gg = acc[2][ct][r] + l1b[512 + d], go = acc[3][ct][r] + l1b[768 + d];
        float cc1 = c1[(size_t)p * 256 + d];
        float c2 = sigm_(gf) * cc1 + sigm_(gi) * tanh_(gg);
        float h2 = sigm_(go) * tanh_(c2);
        c1[(size_t)p * 256 + d] = c2;
        b16_t hb = f2bf(h2);
        hcat[(size_t)p * 512 + 256 + d] = hb;
        dec_out[((size_t)p * 5 + s) * 256 + d] = hb;
      }
  }
}

// ------- logits (M=128 tiles, fused sum(exp), 8 MFMA chains) + extract -------
__global__ __launch_bounds__(512) void k_logits_ext(
    const b16_t* __restrict__ Abf, const b16_t* __restrict__ emb_bf,
    const float* __restrict__ out_b, float* __restrict__ sumexp,
    const int* __restrict__ x_ids, float* __restrict__ tl,
    float* __restrict__ el) {
  int bid = blockIdx.x;
  int tid = threadIdx.x;
  if (bid < 560) {
    // ---- logits: rowBase = (bid%40)*128, tiles [(bid/40)*12, +12) ----
    __shared__ b16_t Bs[64][264];
    int rowBase = (bid % 40) * 128;
    int w = tid >> 6, l = tid & 63, lr = l & 15, kg = l >> 4;
    s16x8 af[8];
    {
      const b16_t* arow = Abf + (size_t)(rowBase + w * 16 + lr) * 256;
#pragma unroll
      for (int kk = 0; kk < 8; ++kk) af[kk] = *(const s16x8*)(arow + kk * 32 + kg * 8);
    }
    float runsum[4] = {0.f, 0.f, 0.f, 0.f};
    int t0 = (bid / 40) * 12, t1 = (t0 + 12 < 157) ? (t0 + 12) : 157;
    for (int tile = t0; tile < t1; ++tile) {
      int colBase = tile * 64;
      __syncthreads();
      for (int i = tid; i < 64 * 32; i += 512) {
        int r = i >> 5, cc = (i & 31) * 8;
        int vrow = colBase + r;
        u16x8 bv = {0, 0, 0, 0, 0, 0, 0, 0};
        if (vrow < V_) bv = *(const u16x8*)(emb_bf + (size_t)vrow * D_ + cc);
        *(u16x8*)&Bs[r][cc] = bv;
      }
      __syncthreads();
      f32x4 acc[4] = {{0.f,0.f,0.f,0.f},{0.f,0.f,0.f,0.f},{0.f,0.f,0.f,0.f},{0.f,0.f,0.f,0.f}};
      f32x4 acc2[4] = {{0.f,0.f,0.f,0.f},{0.f,0.f,0.f,0.f},{0.f,0.f,0.f,0.f},{0.f,0.f,0.f,0.f}};
#pragma unroll
      for (int kk = 0; kk < 4; ++kk) {
#pragma unroll
        for (int f = 0; f < 4; ++f) {
          s16x8 b = *(const s16x8*)&Bs[f * 16 + lr][kk * 32 + kg * 8];
          s16x8 b2 = *(const s16x8*)&Bs[f * 16 + lr][(kk + 4) * 32 + kg * 8];
          acc[f] = __builtin_amdgcn_mfma_f32_16x16x32_bf16(af[kk], b, acc[f], 0, 0, 0);
          acc2[f] = __builtin_amdgcn_mfma_f32_16x16x32_bf16(af[kk + 4], b2, acc2[f], 0, 0, 0);
        }
      }
#pragma unroll
      for (int f = 0; f < 4; ++f) {
        int n = colBase + f * 16 + lr;
        if (n < V_) {
          float ob = out_b[n];
#pragma unroll
          for (int r = 0; r < 4; ++r) runsum[r] += __expf(acc[f][r] + acc2[f][r] + ob);
        }
      }
    }
#pragma unroll
    for (int r = 0; r < 4; ++r) {
      float rs = runsum[r];
      rs += __shfl_xor(rs, 1, 64);
      rs += __shfl_xor(rs, 2, 64);
      rs += __shfl_xor(rs, 4, 64);
      rs += __shfl_xor(rs, 8, 64);
      if (lr == 0) atomicAdd(&sumexp[rowBase + w * 16 + kg * 4 + r], rs);
    }
  } else {
    // ---- extract: 128 blocks x 8 waves, one p per wave ----
    int p = (bid - 560) * 8 + (tid >> 6);
    int lane = tid & 63;
    int t = p >> 3, b = p & 7;
    for (int s = 0; s < S_; ++s) {
      const b16_t* hr = Abf + ((size_t)p * S_ + s) * D_;
      float hv[4];
#pragma unroll
      for (int j = 0; j < 4; ++j) hv[j] = bf2f(hr[lane * 4 + j]);
      if (s < MS_) {
        int pos = t + s; if (pos > T_ - 1) pos = T_ - 1;
        int tok = x_ids[b * (T_ + 2) + pos + 1];
        const b16_t* er = emb_bf + (size_t)tok * D_;
        float ps = 0.f;
#pragma unroll
        for (int j = 0; j < 4; ++j) ps += hv[j] * bf2f(er[lane * 4 + j]);
        for (int m = 1; m < 64; m <<= 1) ps += __shfl_xor(ps, m, 64);
        if (lane == 0) tl[p * MS_ + s] = ps + out_b[tok];
      }
      if (s >= 1) {
        const b16_t* er = emb_bf + (size_t)EOS_ * D_;
        float ps = 0.f;
#pragma unroll
        for (int j = 0; j < 4; ++j) ps += hv[j] * bf2f(er[lane * 4 + j]);
        for (int m = 1; m < 64; m <<= 1) ps += __shfl_xor(ps, m, 64);
        if (lane == 0) el[p * MS_ + (s - 1)] = ps + out_b[EOS_];
      }
    }
  }
}

// ---------------- final: log-probs, DP, loss ----------------
__global__ __launch_bounds__(256) void k_final(const float* __restrict__ sumexp,
                                               const float* __restrict__ tl,
                                               const float* __restrict__ el,
                                               const int* __restrict__ lens,
                                               float* __restrict__ out) {
  __shared__ float logpy[T_][S_][B_];
  __shared__ float alpha[T_ + 1][B_];
  int tid = threadIdx.x;
  for (int p = tid; p < T_ * B_; p += 256) {
    int t = p >> 3, b = p & 7;
    float lz[S_];
#pragma unroll
    for (int s = 0; s < S_; ++s) lz[s] = __logf(sumexp[p * S_ + s]);
    float cum = 0.f, cums[MS_];
#pragma unroll
    for (int s = 0; s < MS_; ++s) {
      float tlp = tl[p * MS_ + s] - lz[s];
      if (t + s < T_) cum += tlp;
      cums[s] = cum;
    }
#pragma unroll
    for (int k = 1; k <= MS_; ++k) {
      float bv = -1000000.0f;
      if (t + k <= T_) bv = cums[k - 1] + (el[p * MS_ + (k - 1)] - lz[k]);
      logpy[t][k][b] = bv;
    }
  }
  __syncthreads();
  if (tid < B_) {
    int b = tid;
    alpha[0][b] = 0.f;
    for (int j = 1; j <= T_; ++j) {
      float vs[MS_], vmax = -1e30f;
#pragma unroll
      for (int k = 1; k <= MS_; ++k) {
        float vv = -2000000.0f;
        if (j - k >= 0) vv = alpha[j - k][b] + logpy[j - k][k][b];
        vs[k - 1] = vv;
        if (vv > vmax) vmax = vv;
      }
      float ssum = 0.f;
#pragma unroll
      for (int k = 0; k < MS_; ++k) ssum += __expf(vs[k] - vmax);
      alpha[j][b] = vmax + __logf(ssum);
    }
  }
  __syncthreads();
  if (tid == 0) {
    float num = 0.f, den = 0.f;
    for (int b = 0; b < B_; ++b) { num += alpha[lens[b]][b]; den += (float)lens[b]; }
    out[0] = -num / den;
  }
}

// ---------------- host ----------------
extern "C" void kernel_launch(void* const* d_in, const int* in_sizes, int n_in,
                              void* d_out, int out_size, void* d_ws, size_t ws_size,
                              hipStream_t stream) {
  const int* x_ids   = (const int*)d_in[0];
  const int* lens    = (const int*)d_in[1];
  const float* emb   = (const float*)d_in[2];
  const float* y_st  = (const float*)d_in[3];
  const float* cWi   = (const float*)d_in[4];
  const float* cWh   = (const float*)d_in[5];
  const float* cb    = (const float*)d_in[6];
  const float* y0W   = (const float*)d_in[7];
  const float* y0b   = (const float*)d_in[8];
  const float* hlW   = (const float*)d_in[9];
  const float* hlb   = (const float*)d_in[10];
  const float* l0Wi  = (const float*)d_in[11];
  const float* l0Wh  = (const float*)d_in[12];
  const float* l0b   = (const float*)d_in[13];
  const float* l1Wi  = (const float*)d_in[14];
  const float* l1Wh  = (const float*)d_in[15];
  const float* l1b   = (const float*)d_in[16];
  const float* outb  = (const float*)d_in[17];
  float* out = (float*)d_out;
  (void)in_sizes; (void)n_in; (void)out_size; (void)ws_size;

  char* ws = (char*)d_ws;
  size_t cur = 0;
  auto alloc = [&](size_t bytes) { size_t o = cur; cur += (bytes + 255) & ~(size_t)255; return o; };
  b16_t* emb_bf    = (b16_t*)(ws + alloc((size_t)V_ * D_ * 2));
  b16_t* cWi_bf    = (b16_t*)(ws + alloc(1024 * 256 * 2));
  b16_t* y0W_bf    = (b16_t*)(ws + alloc(256 * 256 * 2));
  b16_t* hlW_bf    = (b16_t*)(ws + alloc(512 * 256 * 2));
  b16_t* l0Wi_bf   = (b16_t*)(ws + alloc(1024 * 256 * 2));
  b16_t* l0Wh_bf   = (b16_t*)(ws + alloc(1024 * 256 * 2));
  b16_t* Wcat_bf   = (b16_t*)(ws + alloc(1024 * 512 * 2));
  unsigned* Whf    = (unsigned*)(ws + alloc(1024 * 128 * 4));
  b16_t* seq_bf    = (b16_t*)(ws + alloc(1024 * 256 * 2));
  float* encX      = (float*)(ws + alloc((size_t)1024 * 1024 * 4));
  b16_t* droph_bf  = (b16_t*)(ws + alloc(1024 * 256 * 2));
  b16_t* hcat      = (b16_t*)(ws + alloc(1024 * 512 * 2));
  b16_t* seg_bf    = (b16_t*)(ws + alloc((size_t)5120 * 256 * 2));
  float* X0        = (float*)(ws + alloc((size_t)5120 * 1024 * 4));
  float* c0        = (float*)(ws + alloc((size_t)2 * 1024 * 256 * 4));
  float* c1        = c0 + 1024 * 256;
  b16_t* dec_h_bf  = (b16_t*)(ws + alloc((size_t)5120 * 256 * 2));
  float* sumexp    = (float*)(ws + alloc(5120 * 4));                 // 20480 B
  unsigned* hglob  = (unsigned*)(ws + alloc((size_t)128 * 8 * 4 * 32 * 4)); // 524288 B
  float* tl        = (float*)(ws + alloc(1024 * MS_ * 4));
  float* el        = (float*)(ws + alloc(1024 * MS_ * 4));

  hipMemsetAsync(sumexp, 0, 20480 + 524288, stream);  // sumexp + hglob (value-based sync)
  hipMemsetAsync(c0, 0, (size_t)2 * 1024 * 256 * 4, stream);

  k_prep<<<1024, 256, 0, stream>>>(emb, cWi, y0W, hlW, l0Wi, l0Wh, l1Wi, l1Wh, cWh,
                                   x_ids, y_st,
                                   emb_bf, cWi_bf, y0W_bf, hlW_bf, l0Wi_bf, l0Wh_bf,
                                   Wcat_bf, Whf, seq_bf, seg_bf);

  // encX = seq @ cWi^T + cb (plain stores -> L2-cached for the encoder)
  k_gemm<<<dim3(16, 16), 256, 0, stream>>>(seq_bf, 256, cWi_bf, cb, encX, 1024);
  // encoder v9 (blocks 0..31) + X0 s>=1 GEMM (blocks 32..1055), one launch
  k_enc_x0<<<1056, 512, 0, stream>>>(Whf, encX, hglob, droph_bf,
                                     seg_bf, l0Wi_bf, l0b, X0);

  // y_in0 -> seg s=0, hlin -> hcat, X0 s=0 GEMM (one launch)
  k_proj<<<dim3(16, 28), 256, 0, stream>>>(droph_bf, y0W_bf, y0b, hlW_bf, hlb,
                                           seg_bf, hcat, l0Wi_bf, l0b, X0);

  for (int s = 0; s < S_; ++s)
    k_dec2<<<64, 512, 0, stream>>>(hcat, l0Wh_bf, Wcat_bf, X0, l1b, c0, c1, dec_h_bf, s);

  // logits + extract (one launch)
  k_logits_ext<<<688, 512, 0, stream>>>(dec_h_bf, emb_bf, outb, sumexp,
                                        x_ids, tl, el);
  k_final<<<1, 256, 0, stream>>>(sumexp, tl, el, lens, out);
}